// Round 5
// baseline (136.766 us; speedup 1.0000x reference)
//
#include <hip/hip_runtime.h>
#include <math.h>

#define S_LEN 1024
#define DM    256
#define DU    32
#define TEMPF 5.0f
#define NS    4          // attention j-splits (flash-decoding style)

// ---------------------------------------------------------------------------
// Kernel A: fused QKV projection.  out = act(x @ W + b), act = sigmoid for
// Q,K (mat 0,1), identity for V (mat 2). Writes [h][s][du] layout.
// 32x64 tile, 64 threads (1 wave), 4x8 micro, BK=32, single-barrier dbuf.
// Grid (12 n-tiles over 768 cols, 32 m-tiles) = 384 blocks.
// ---------------------------------------------------------------------------
__global__ __launch_bounds__(64) void qkv_proj_kernel(
    const float* __restrict__ x,
    const float* __restrict__ Wq, const float* __restrict__ bq,
    const float* __restrict__ Wk, const float* __restrict__ bk,
    const float* __restrict__ Wv, const float* __restrict__ bv,
    float* __restrict__ qo, float* __restrict__ ko, float* __restrict__ vo)
{
    const int n0g = blockIdx.x * 64;      // 0..704 over [Wq|Wk|Wv] cols
    const int mat = n0g >> 8;
    const int n0  = n0g & 255;
    const float* __restrict__ W    = (mat == 0) ? Wq : ((mat == 1) ? Wk : Wv);
    const float* __restrict__ bias = (mat == 0) ? bq : ((mat == 1) ? bk : bv);
    float* __restrict__ dst        = (mat == 0) ? qo : ((mat == 1) ? ko : vo);

    const int m0 = blockIdx.y * 32;
    const int t  = threadIdx.x;
    const int tx = t & 7;         // cols tx*8..+7
    const int ty = t >> 3;        // rows ty*4..+3

    __shared__ float xs[2][32][36];   // transposed [k][m]
    __shared__ float wsh[2][32][68];  // [k][n]

    float acc[4][8] = {};

    const int srow = t >> 1;          // 0..31
    const int sxk  = (t & 1) * 16;    // x k-offset within BK
    const int swn  = (t & 1) * 32;    // W n-offset within 64

    float4 xp[4], wp[8];
    #pragma unroll
    for (int i = 0; i < 4; i++)
        xp[i] = *(const float4*)&x[(m0 + srow) * DM + sxk + i * 4];
    #pragma unroll
    for (int j = 0; j < 8; j++)
        wp[j] = *(const float4*)&W[srow * DM + n0 + swn + j * 4];

    int buf = 0;
    // store tile 0
    #pragma unroll
    for (int i = 0; i < 4; i++) {
        xs[0][sxk + i*4 + 0][srow] = xp[i].x; xs[0][sxk + i*4 + 1][srow] = xp[i].y;
        xs[0][sxk + i*4 + 2][srow] = xp[i].z; xs[0][sxk + i*4 + 3][srow] = xp[i].w;
    }
    #pragma unroll
    for (int j = 0; j < 8; j++)
        *(float4*)&wsh[0][srow][swn + j * 4] = wp[j];
    __syncthreads();

    for (int step = 0; step < 8; step++) {
        if (step < 7) {
            const int k0 = (step + 1) * 32;
            #pragma unroll
            for (int i = 0; i < 4; i++)
                xp[i] = *(const float4*)&x[(m0 + srow) * DM + k0 + sxk + i * 4];
            #pragma unroll
            for (int j = 0; j < 8; j++)
                wp[j] = *(const float4*)&W[(k0 + srow) * DM + n0 + swn + j * 4];
        }
        #pragma unroll
        for (int kk = 0; kk < 32; kk++) {
            float4 a4 = *(const float4*)&xs[buf][kk][ty * 4];
            float4 b0 = *(const float4*)&wsh[buf][kk][tx * 8];
            float4 b1 = *(const float4*)&wsh[buf][kk][tx * 8 + 4];
            const float bb[8] = {b0.x,b0.y,b0.z,b0.w,b1.x,b1.y,b1.z,b1.w};
            const float aa[4] = {a4.x,a4.y,a4.z,a4.w};
            #pragma unroll
            for (int i = 0; i < 4; i++)
                #pragma unroll
                for (int j = 0; j < 8; j++)
                    acc[i][j] += aa[i] * bb[j];
        }
        if (step < 7) {
            const int nb = buf ^ 1;
            #pragma unroll
            for (int i = 0; i < 4; i++) {
                xs[nb][sxk + i*4 + 0][srow] = xp[i].x; xs[nb][sxk + i*4 + 1][srow] = xp[i].y;
                xs[nb][sxk + i*4 + 2][srow] = xp[i].z; xs[nb][sxk + i*4 + 3][srow] = xp[i].w;
            }
            #pragma unroll
            for (int j = 0; j < 8; j++)
                *(float4*)&wsh[nb][srow][swn + j * 4] = wp[j];
            __syncthreads();
            buf = nb;
        }
    }

    // epilogue: bias (+sigmoid), store to [h][s][du]
    const int colb = n0 + tx * 8;
    const int hh   = colb >> 5;
    const int dd0  = colb & 31;
    float4 bb0 = *(const float4*)&bias[colb];
    float4 bb1 = *(const float4*)&bias[colb + 4];
    #pragma unroll
    for (int i = 0; i < 4; i++) {
        const int row = m0 + ty * 4 + i;
        float4 v0 = make_float4(acc[i][0] + bb0.x, acc[i][1] + bb0.y,
                                acc[i][2] + bb0.z, acc[i][3] + bb0.w);
        float4 v1 = make_float4(acc[i][4] + bb1.x, acc[i][5] + bb1.y,
                                acc[i][6] + bb1.z, acc[i][7] + bb1.w);
        if (mat < 2) {
            v0.x = 1.0f/(1.0f+__expf(-v0.x)); v0.y = 1.0f/(1.0f+__expf(-v0.y));
            v0.z = 1.0f/(1.0f+__expf(-v0.z)); v0.w = 1.0f/(1.0f+__expf(-v0.w));
            v1.x = 1.0f/(1.0f+__expf(-v1.x)); v1.y = 1.0f/(1.0f+__expf(-v1.y));
            v1.z = 1.0f/(1.0f+__expf(-v1.z)); v1.w = 1.0f/(1.0f+__expf(-v1.w));
        }
        float* dp = dst + hh * (S_LEN * DU) + row * DU + dd0;
        *(float4*)dp       = v0;
        *(float4*)(dp + 4) = v1;
    }
}

// ---------------------------------------------------------------------------
// Kernel B: fuzzy-implication attention, causal, j-split, NO online max.
// z = TEMP*(1 - mean relu(Q-K)) is in [0,5] -> exp(z) <= 148.4, safe with
// fixed m=0. Partial (o, l) per split; combine sums.
// Grid: 8h x 16 i-tiles(64 rows) x NS = 512 blocks (heavy i-tiles first).
// Thread (r,c): rows {r,r+16,r+32,r+48}, dims {c,c+16}, score cols c+16*q4.
// V packed j-major: Vs4[j>>2][d>=16][d&15][j&3] -> b128 serves 4 j, all rows.
// ---------------------------------------------------------------------------
__global__ __launch_bounds__(256, 2) void attn_kernel(
    const float* __restrict__ q, const float* __restrict__ k,
    const float* __restrict__ v,
    float* __restrict__ part_o, float* __restrict__ part_l)
{
    const int bid = blockIdx.x;
    const int it4 = 15 - (bid >> 5);      // LPT: heavy first
    const int sub = bid & 31;
    const int h   = sub & 7;
    const int s   = sub >> 3;             // split 0..NS-1
    const int t   = threadIdx.x;
    const int r   = t >> 4;               // 0..15
    const int c   = t & 15;               // 0..15
    const int i0  = it4 * 64;

    __shared__ float  Ks[64][36];
    __shared__ float4 Vs4[16][2][17];     // [j4][half][c] components = j4*4+0..3
    __shared__ float  Ps[64][68];

    float qreg[4][32];
    #pragma unroll
    for (int kq = 0; kq < 4; kq++) {
        const float* qrow = q + h * (S_LEN * DU) + (i0 + r + 16 * kq) * DU;
        #pragma unroll
        for (int d4 = 0; d4 < 8; d4++) {
            float4 qv = *(const float4*)&qrow[d4 * 4];
            qreg[kq][d4*4+0] = qv.x; qreg[kq][d4*4+1] = qv.y;
            qreg[kq][d4*4+2] = qv.z; qreg[kq][d4*4+3] = qv.w;
        }
    }

    float o0[4] = {0,0,0,0}, o1[4] = {0,0,0,0}, lpart[4] = {0,0,0,0};

    const int jr = t >> 2;            // 0..63 staging row
    const int d0 = (t & 3) * 8;       // staging d-offset
    const float* kbase = k + h * (S_LEN * DU);
    const float* vbase = v + h * (S_LEN * DU);

    const int njt = it4 + 1;
    float4 ka, kb, va, vb;
    if (s < njt) {
        const float* kp = kbase + (s * 64 + jr) * DU + d0;
        const float* vp = vbase + (s * 64 + jr) * DU + d0;
        ka = *(const float4*)kp; kb = *(const float4*)(kp + 4);
        va = *(const float4*)vp; vb = *(const float4*)(vp + 4);
    }

    for (int jt = s; jt < njt; jt += NS) {
        __syncthreads();   // everyone done reading previous tile
        *(float4*)&Ks[jr][d0]     = ka;
        *(float4*)&Ks[jr][d0 + 4] = kb;
        {
            float vv[8] = {va.x, va.y, va.z, va.w, vb.x, vb.y, vb.z, vb.w};
            #pragma unroll
            for (int i = 0; i < 8; i++) {
                const int d = d0 + i;
                ((float*)&Vs4[jr >> 2][d >> 4][d & 15])[jr & 3] = vv[i];
            }
        }
        __syncthreads();
        if (jt + NS < njt) {          // prefetch next tile (hidden by compute)
            const float* kp = kbase + ((jt + NS) * 64 + jr) * DU + d0;
            const float* vp = vbase + ((jt + NS) * 64 + jr) * DU + d0;
            ka = *(const float4*)kp; kb = *(const float4*)(kp + 4);
            va = *(const float4*)vp; vb = *(const float4*)(vp + 4);
        }

        // ---- scores: 4 cols x 4 rows, Ks reads shared across rows ----
        #pragma unroll
        for (int q4 = 0; q4 < 4; q4++) {
            const int jj  = c + q4 * 16;
            const int jgl = jt * 64 + jj;
            float sacc[4] = {0,0,0,0};
            #pragma unroll
            for (int d = 0; d < 32; d += 4) {
                float4 k4 = *(const float4*)&Ks[jj][d];
                #pragma unroll
                for (int kq = 0; kq < 4; kq++) {
                    sacc[kq] += fmaxf(qreg[kq][d+0] - k4.x, 0.0f)
                              + fmaxf(qreg[kq][d+1] - k4.y, 0.0f)
                              + fmaxf(qreg[kq][d+2] - k4.z, 0.0f)
                              + fmaxf(qreg[kq][d+3] - k4.w, 0.0f);
                }
            }
            #pragma unroll
            for (int kq = 0; kq < 4; kq++) {
                const int ig = i0 + r + 16 * kq;
                const float p = (jgl <= ig)
                    ? __expf(TEMPF - (TEMPF / 32.0f) * sacc[kq]) : 0.0f;
                lpart[kq] += p;
                Ps[r + 16 * kq][jj] = p;   // intra-wave only -> no barrier
            }
        }

        // ---- PV: V b128 serves 4 j for all rows ----
        #pragma unroll 4
        for (int j4 = 0; j4 < 16; j4++) {
            float4 vA = Vs4[j4][0][c];     // V[4j4+0..3][c]
            float4 vB = Vs4[j4][1][c];     // V[4j4+0..3][c+16]
            #pragma unroll
            for (int kq = 0; kq < 4; kq++) {
                float4 pj = *(const float4*)&Ps[r + 16 * kq][j4 * 4];
                o0[kq] += pj.x*vA.x + pj.y*vA.y + pj.z*vA.z + pj.w*vA.w;
                o1[kq] += pj.x*vB.x + pj.y*vB.y + pj.z*vB.z + pj.w*vB.w;
            }
        }
    }

    // l: sum each row's partials over the 16 lanes
    #pragma unroll
    for (int off = 8; off; off >>= 1)
        #pragma unroll
        for (int kq = 0; kq < 4; kq++)
            lpart[kq] += __shfl_xor(lpart[kq], off, 16);

    const int pbase = (h * 16 + it4) * NS + s;
    float* po = part_o + pbase * 2048;
    #pragma unroll
    for (int kq = 0; kq < 4; kq++) {
        po[(r + 16 * kq) * 32 + c]      = o0[kq];
        po[(r + 16 * kq) * 32 + c + 16] = o1[kq];
    }
    if (c == 0) {
        #pragma unroll
        for (int kq = 0; kq < 4; kq++)
            part_l[pbase * 64 + r + 16 * kq] = lpart[kq];
    }
}

// ---------------------------------------------------------------------------
// Kernel B2: combine split partials (plain sums; no max bookkeeping).
// Grid 128 = 8h x 16 i-tiles, 256 threads.
// ---------------------------------------------------------------------------
__global__ __launch_bounds__(256) void combine_kernel(
    const float* __restrict__ part_o, const float* __restrict__ part_l,
    float* __restrict__ attn)
{
    const int h    = blockIdx.x & 7;
    const int it4  = blockIdx.x >> 3;
    const int t    = threadIdx.x;
    const int r    = t >> 4;
    const int c    = t & 15;
    const int base = (h * 16 + it4) * NS;

    #pragma unroll
    for (int kq = 0; kq < 4; kq++) {
        const int row = r + 16 * kq;
        float os0 = 0.0f, os1 = 0.0f, ls = 0.0f;
        #pragma unroll
        for (int s2 = 0; s2 < NS; s2++) {
            const float* po = part_o + (base + s2) * 2048;
            os0 += po[row * 32 + c];
            os1 += po[row * 32 + c + 16];
            ls  += part_l[(base + s2) * 64 + row];
        }
        const float inv = 1.0f / ls;
        attn[(it4 * 64 + row) * DM + h * DU + c]      = os0 * inv;
        attn[(it4 * 64 + row) * DM + h * DU + c + 16] = os1 * inv;
    }
}

// ---------------------------------------------------------------------------
// Kernel C: output projection  out = attn @ Wo + bo.
// 32x32 tile, 64 threads, 4x4 micro (VALU-bound), dbuf, 256 blocks.
// ---------------------------------------------------------------------------
__global__ __launch_bounds__(64) void out_proj_kernel(
    const float* __restrict__ a, const float* __restrict__ W,
    const float* __restrict__ bias, float* __restrict__ dst)
{
    const int n0 = blockIdx.x * 32;
    const int m0 = blockIdx.y * 32;
    const int t  = threadIdx.x;
    const int tx = t & 7;         // cols tx*4..+3
    const int ty = t >> 3;        // rows ty*4..+3

    __shared__ float xs[2][32][36];   // transposed [k][m]
    __shared__ float wsh[2][32][36];  // [k][n]

    float acc[4][4] = {};

    const int srow = t >> 1;
    const int sk   = (t & 1) * 16;

    float4 xp[4], wp[4];
    #pragma unroll
    for (int i = 0; i < 4; i++) {
        xp[i] = *(const float4*)&a[(m0 + srow) * DM + sk + i * 4];
        wp[i] = *(const float4*)&W[srow * DM + n0 + (t & 1) * 16 + i * 4];
    }

    int buf = 0;
    #pragma unroll
    for (int i = 0; i < 4; i++) {
        xs[0][sk + i*4 + 0][srow] = xp[i].x; xs[0][sk + i*4 + 1][srow] = xp[i].y;
        xs[0][sk + i*4 + 2][srow] = xp[i].z; xs[0][sk + i*4 + 3][srow] = xp[i].w;
        *(float4*)&wsh[0][srow][(t & 1) * 16 + i * 4] = wp[i];
    }
    __syncthreads();

    for (int step = 0; step < 8; step++) {
        if (step < 7) {
            const int k0 = (step + 1) * 32;
            #pragma unroll
            for (int i = 0; i < 4; i++) {
                xp[i] = *(const float4*)&a[(m0 + srow) * DM + k0 + sk + i * 4];
                wp[i] = *(const float4*)&W[(k0 + srow) * DM + n0 + (t & 1) * 16 + i * 4];
            }
        }
        #pragma unroll
        for (int kk = 0; kk < 32; kk++) {
            float4 a4 = *(const float4*)&xs[buf][kk][ty * 4];
            float4 b4 = *(const float4*)&wsh[buf][kk][tx * 4];
            acc[0][0] += a4.x * b4.x; acc[0][1] += a4.x * b4.y;
            acc[0][2] += a4.x * b4.z; acc[0][3] += a4.x * b4.w;
            acc[1][0] += a4.y * b4.x; acc[1][1] += a4.y * b4.y;
            acc[1][2] += a4.y * b4.z; acc[1][3] += a4.y * b4.w;
            acc[2][0] += a4.z * b4.x; acc[2][1] += a4.z * b4.y;
            acc[2][2] += a4.z * b4.z; acc[2][3] += a4.z * b4.w;
            acc[3][0] += a4.w * b4.x; acc[3][1] += a4.w * b4.y;
            acc[3][2] += a4.w * b4.z; acc[3][3] += a4.w * b4.w;
        }
        if (step < 7) {
            const int nb = buf ^ 1;
            #pragma unroll
            for (int i = 0; i < 4; i++) {
                xs[nb][sk + i*4 + 0][srow] = xp[i].x; xs[nb][sk + i*4 + 1][srow] = xp[i].y;
                xs[nb][sk + i*4 + 2][srow] = xp[i].z; xs[nb][sk + i*4 + 3][srow] = xp[i].w;
                *(float4*)&wsh[nb][srow][(t & 1) * 16 + i * 4] = wp[i];
            }
            __syncthreads();
            buf = nb;
        }
    }

    float4 bb = *(const float4*)&bias[n0 + tx * 4];
    #pragma unroll
    for (int i = 0; i < 4; i++) {
        const int row = m0 + ty * 4 + i;
        float4 v4 = make_float4(acc[i][0] + bb.x, acc[i][1] + bb.y,
                                acc[i][2] + bb.z, acc[i][3] + bb.w);
        *(float4*)&dst[row * DM + n0 + tx * 4] = v4;
    }
}

// ---------------------------------------------------------------------------
extern "C" void kernel_launch(void* const* d_in, const int* in_sizes, int n_in,
                              void* d_out, int out_size, void* d_ws, size_t ws_size,
                              hipStream_t stream)
{
    const float* x  = (const float*)d_in[0];
    const float* Wq = (const float*)d_in[1];
    const float* bq = (const float*)d_in[2];
    const float* Wk = (const float*)d_in[3];
    const float* bk = (const float*)d_in[4];
    const float* Wv = (const float*)d_in[5];
    const float* bv = (const float*)d_in[6];
    const float* Wo = (const float*)d_in[7];
    const float* bo = (const float*)d_in[8];
    float* out = (float*)d_out;

    float* ws      = (float*)d_ws;
    float* q       = ws;                      // [8][1024][32] = 262144
    float* k       = q + 262144;
    float* v       = k + 262144;
    float* attn    = v + 262144;              // [1024][256]  = 262144
    float* part_o  = attn + 262144;           // 8*16*NS*2048 = 1048576
    float* part_l  = part_o + 1048576;        // 8*16*NS*64   = 32768
    // total ~8.5 MB

    qkv_proj_kernel<<<dim3(12, 32), 64, 0, stream>>>(x, Wq, bq, Wk, bk, Wv, bv, q, k, v);
    attn_kernel<<<dim3(512), 256, 0, stream>>>(q, k, v, part_o, part_l);
    combine_kernel<<<dim3(128), 256, 0, stream>>>(part_o, part_l, attn);
    out_proj_kernel<<<dim3(8, 32), 64, 0, stream>>>(attn, Wo, bo, out);
}

// Round 6
// 118.579 us; speedup vs baseline: 1.1534x; 1.1534x over previous
//
#include <hip/hip_runtime.h>
#include <math.h>

#define S_LEN 1024
#define DM    256
#define DU    32
#define TEMPF 5.0f
#define NS    4          // attention j-splits (flash-decoding style)

// ---------------------------------------------------------------------------
// Kernel A: fused QKV projection.  out = act(x @ W + b), act = sigmoid for
// Q,K (mat 0,1), identity for V (mat 2). Writes [h][s][du] layout to ws.
// 32x64 tile, BK=32, 256 threads (4 waves), double-buffered LDS, 384 blocks.
// (Reverted to round-4 version: 64-thread blocks starved TLP — +17 us.)
// ---------------------------------------------------------------------------
__global__ __launch_bounds__(256) void qkv_proj_kernel(
    const float* __restrict__ x,
    const float* __restrict__ Wq, const float* __restrict__ bq,
    const float* __restrict__ Wk, const float* __restrict__ bk,
    const float* __restrict__ Wv, const float* __restrict__ bv,
    float* __restrict__ qo, float* __restrict__ ko, float* __restrict__ vo)
{
    const int mat = blockIdx.z;
    const float* __restrict__ W    = (mat == 0) ? Wq : ((mat == 1) ? Wk : Wv);
    const float* __restrict__ bias = (mat == 0) ? bq : ((mat == 1) ? bk : bv);
    float* __restrict__ dst        = (mat == 0) ? qo : ((mat == 1) ? ko : vo);

    const int n0 = blockIdx.x * 64;
    const int m0 = blockIdx.y * 32;
    const int t  = threadIdx.x;
    const int tx = t & 15;        // cols tx*4..tx*4+3
    const int ty = t >> 4;        // rows ty*2, ty*2+1

    __shared__ float xs[2][32][36];   // transposed [k][row]
    __shared__ float wsh[2][32][68];  // [k][n]

    float acc[2][4] = {};

    const int xrow = t & 31;          // 0..31
    const int xkc  = (t >> 5) * 4;    // 0..28
    const int wrow = t >> 4;          // 0..15 (+16)
    const int wcol = (t & 15) * 4;

    // stage tile 0
    float4 xa = *(const float4*)&x[(m0 + xrow) * DM + xkc];
    float4 wa = *(const float4*)&W[wrow * DM + n0 + wcol];
    float4 wb = *(const float4*)&W[(wrow + 16) * DM + n0 + wcol];
    xs[0][xkc + 0][xrow] = xa.x; xs[0][xkc + 1][xrow] = xa.y;
    xs[0][xkc + 2][xrow] = xa.z; xs[0][xkc + 3][xrow] = xa.w;
    *(float4*)&wsh[0][wrow][wcol]      = wa;
    *(float4*)&wsh[0][wrow + 16][wcol] = wb;
    __syncthreads();

    int cur = 0;
    for (int k0 = 32; k0 < DM; k0 += 32) {
        // prefetch next tile (independent of compute; compiler hoists)
        xa = *(const float4*)&x[(m0 + xrow) * DM + k0 + xkc];
        wa = *(const float4*)&W[(k0 + wrow) * DM + n0 + wcol];
        wb = *(const float4*)&W[(k0 + wrow + 16) * DM + n0 + wcol];
        #pragma unroll
        for (int kk = 0; kk < 32; kk++) {
            float2 a2 = *(const float2*)&xs[cur][kk][ty * 2];
            float4 b4 = *(const float4*)&wsh[cur][kk][tx * 4];
            acc[0][0] += a2.x * b4.x; acc[0][1] += a2.x * b4.y;
            acc[0][2] += a2.x * b4.z; acc[0][3] += a2.x * b4.w;
            acc[1][0] += a2.y * b4.x; acc[1][1] += a2.y * b4.y;
            acc[1][2] += a2.y * b4.z; acc[1][3] += a2.y * b4.w;
        }
        const int nxt = cur ^ 1;
        xs[nxt][xkc + 0][xrow] = xa.x; xs[nxt][xkc + 1][xrow] = xa.y;
        xs[nxt][xkc + 2][xrow] = xa.z; xs[nxt][xkc + 3][xrow] = xa.w;
        *(float4*)&wsh[nxt][wrow][wcol]      = wa;
        *(float4*)&wsh[nxt][wrow + 16][wcol] = wb;
        __syncthreads();
        cur = nxt;
    }
    #pragma unroll
    for (int kk = 0; kk < 32; kk++) {
        float2 a2 = *(const float2*)&xs[cur][kk][ty * 2];
        float4 b4 = *(const float4*)&wsh[cur][kk][tx * 4];
        acc[0][0] += a2.x * b4.x; acc[0][1] += a2.x * b4.y;
        acc[0][2] += a2.x * b4.z; acc[0][3] += a2.x * b4.w;
        acc[1][0] += a2.y * b4.x; acc[1][1] += a2.y * b4.y;
        acc[1][2] += a2.y * b4.z; acc[1][3] += a2.y * b4.w;
    }

    #pragma unroll
    for (int j = 0; j < 4; j++) {
        const int cidx = n0 + tx * 4 + j;
        const float bb = bias[cidx];
        const int hh = cidx >> 5;
        const int dd = cidx & 31;
        #pragma unroll
        for (int i = 0; i < 2; i++) {
            const int row = m0 + ty * 2 + i;
            float val = acc[i][j] + bb;
            if (mat < 2) val = 1.0f / (1.0f + __expf(-val));   // sigmoid
            dst[hh * (S_LEN * DU) + row * DU + dd] = val;
        }
    }
}

// ---------------------------------------------------------------------------
// Kernel B: fuzzy-implication attention, causal, j-split, NO online max.
// z = TEMP*(1 - mean relu(Q-K)) is in [0,5] -> exp(z) <= 148.4, safe with
// fixed m=0. Partial (o, l) per split; combine sums.
// Grid: 8h x 16 i-tiles(64 rows) x NS = 512 blocks (heavy i-tiles first).
// Thread (r,c): rows {r,r+16,r+32,r+48}, dims {c,c+16}, score cols c+16*q4.
// V packed j-major: Vs4[j>>2][d>=16][d&15][j&3] -> b128 serves 4 j, all rows.
// ---------------------------------------------------------------------------
__global__ __launch_bounds__(256, 2) void attn_kernel(
    const float* __restrict__ q, const float* __restrict__ k,
    const float* __restrict__ v,
    float* __restrict__ part_o, float* __restrict__ part_l)
{
    const int bid = blockIdx.x;
    const int it4 = 15 - (bid >> 5);      // LPT: heavy first
    const int sub = bid & 31;
    const int h   = sub & 7;
    const int s   = sub >> 3;             // split 0..NS-1
    const int t   = threadIdx.x;
    const int r   = t >> 4;               // 0..15
    const int c   = t & 15;               // 0..15
    const int i0  = it4 * 64;

    __shared__ float  Ks[64][36];
    __shared__ float4 Vs4[16][2][17];     // [j4][half][c] components = j4*4+0..3
    __shared__ float  Ps[64][68];

    float qreg[4][32];
    #pragma unroll
    for (int kq = 0; kq < 4; kq++) {
        const float* qrow = q + h * (S_LEN * DU) + (i0 + r + 16 * kq) * DU;
        #pragma unroll
        for (int d4 = 0; d4 < 8; d4++) {
            float4 qv = *(const float4*)&qrow[d4 * 4];
            qreg[kq][d4*4+0] = qv.x; qreg[kq][d4*4+1] = qv.y;
            qreg[kq][d4*4+2] = qv.z; qreg[kq][d4*4+3] = qv.w;
        }
    }

    float o0[4] = {0,0,0,0}, o1[4] = {0,0,0,0}, lpart[4] = {0,0,0,0};

    const int jr = t >> 2;            // 0..63 staging row
    const int d0 = (t & 3) * 8;       // staging d-offset
    const float* kbase = k + h * (S_LEN * DU);
    const float* vbase = v + h * (S_LEN * DU);

    const int njt = it4 + 1;
    float4 ka, kb, va, vb;
    if (s < njt) {
        const float* kp = kbase + (s * 64 + jr) * DU + d0;
        const float* vp = vbase + (s * 64 + jr) * DU + d0;
        ka = *(const float4*)kp; kb = *(const float4*)(kp + 4);
        va = *(const float4*)vp; vb = *(const float4*)(vp + 4);
    }

    for (int jt = s; jt < njt; jt += NS) {
        __syncthreads();   // everyone done reading previous tile
        *(float4*)&Ks[jr][d0]     = ka;
        *(float4*)&Ks[jr][d0 + 4] = kb;
        {
            float vv[8] = {va.x, va.y, va.z, va.w, vb.x, vb.y, vb.z, vb.w};
            #pragma unroll
            for (int i = 0; i < 8; i++) {
                const int d = d0 + i;
                ((float*)&Vs4[jr >> 2][d >> 4][d & 15])[jr & 3] = vv[i];
            }
        }
        __syncthreads();
        if (jt + NS < njt) {          // prefetch next tile (hidden by compute)
            const float* kp = kbase + ((jt + NS) * 64 + jr) * DU + d0;
            const float* vp = vbase + ((jt + NS) * 64 + jr) * DU + d0;
            ka = *(const float4*)kp; kb = *(const float4*)(kp + 4);
            va = *(const float4*)vp; vb = *(const float4*)(vp + 4);
        }

        // ---- scores: 4 cols x 4 rows, Ks reads shared across rows ----
        #pragma unroll
        for (int q4 = 0; q4 < 4; q4++) {
            const int jj  = c + q4 * 16;
            const int jgl = jt * 64 + jj;
            float sacc[4] = {0,0,0,0};
            #pragma unroll
            for (int d = 0; d < 32; d += 4) {
                float4 k4 = *(const float4*)&Ks[jj][d];
                #pragma unroll
                for (int kq = 0; kq < 4; kq++) {
                    sacc[kq] += fmaxf(qreg[kq][d+0] - k4.x, 0.0f)
                              + fmaxf(qreg[kq][d+1] - k4.y, 0.0f)
                              + fmaxf(qreg[kq][d+2] - k4.z, 0.0f)
                              + fmaxf(qreg[kq][d+3] - k4.w, 0.0f);
                }
            }
            #pragma unroll
            for (int kq = 0; kq < 4; kq++) {
                const int ig = i0 + r + 16 * kq;
                const float p = (jgl <= ig)
                    ? __expf(TEMPF - (TEMPF / 32.0f) * sacc[kq]) : 0.0f;
                lpart[kq] += p;
                Ps[r + 16 * kq][jj] = p;   // intra-wave only -> no barrier
            }
        }

        // ---- PV: V b128 serves 4 j for all rows ----
        #pragma unroll 4
        for (int j4 = 0; j4 < 16; j4++) {
            float4 vA = Vs4[j4][0][c];     // V[4j4+0..3][c]
            float4 vB = Vs4[j4][1][c];     // V[4j4+0..3][c+16]
            #pragma unroll
            for (int kq = 0; kq < 4; kq++) {
                float4 pj = *(const float4*)&Ps[r + 16 * kq][j4 * 4];
                o0[kq] += pj.x*vA.x + pj.y*vA.y + pj.z*vA.z + pj.w*vA.w;
                o1[kq] += pj.x*vB.x + pj.y*vB.y + pj.z*vB.z + pj.w*vB.w;
            }
        }
    }

    // l: sum each row's partials over the 16 lanes
    #pragma unroll
    for (int off = 8; off; off >>= 1)
        #pragma unroll
        for (int kq = 0; kq < 4; kq++)
            lpart[kq] += __shfl_xor(lpart[kq], off, 16);

    const int pbase = (h * 16 + it4) * NS + s;
    float* po = part_o + pbase * 2048;
    #pragma unroll
    for (int kq = 0; kq < 4; kq++) {
        po[(r + 16 * kq) * 32 + c]      = o0[kq];
        po[(r + 16 * kq) * 32 + c + 16] = o1[kq];
    }
    if (c == 0) {
        #pragma unroll
        for (int kq = 0; kq < 4; kq++)
            part_l[pbase * 64 + r + 16 * kq] = lpart[kq];
    }
}

// ---------------------------------------------------------------------------
// Kernel B2: combine split partials (plain sums; no max bookkeeping).
// Grid 128 = 8h x 16 i-tiles, 256 threads.
// ---------------------------------------------------------------------------
__global__ __launch_bounds__(256) void combine_kernel(
    const float* __restrict__ part_o, const float* __restrict__ part_l,
    float* __restrict__ attn)
{
    const int h    = blockIdx.x & 7;
    const int it4  = blockIdx.x >> 3;
    const int t    = threadIdx.x;
    const int r    = t >> 4;
    const int c    = t & 15;
    const int base = (h * 16 + it4) * NS;

    #pragma unroll
    for (int kq = 0; kq < 4; kq++) {
        const int row = r + 16 * kq;
        float os0 = 0.0f, os1 = 0.0f, ls = 0.0f;
        #pragma unroll
        for (int s2 = 0; s2 < NS; s2++) {
            const float* po = part_o + (base + s2) * 2048;
            os0 += po[row * 32 + c];
            os1 += po[row * 32 + c + 16];
            ls  += part_l[(base + s2) * 64 + row];
        }
        const float inv = 1.0f / ls;
        attn[(it4 * 64 + row) * DM + h * DU + c]      = os0 * inv;
        attn[(it4 * 64 + row) * DM + h * DU + c + 16] = os1 * inv;
    }
}

// ---------------------------------------------------------------------------
// Kernel C: output projection  out = attn @ Wo + bo.  32x32 tiles, dbuf,
// 256 threads (4 waves), 256 blocks.  (Reverted to round-4 version.)
// ---------------------------------------------------------------------------
__global__ __launch_bounds__(256) void out_proj_kernel(
    const float* __restrict__ a, const float* __restrict__ W,
    const float* __restrict__ bias, float* __restrict__ dst)
{
    const int n0 = blockIdx.x * 32;
    const int m0 = blockIdx.y * 32;
    const int t  = threadIdx.x;
    const int tx = t & 15;        // cols tx*2, tx*2+1
    const int ty = t >> 4;        // rows ty*2, ty*2+1

    __shared__ float xs[2][32][36];   // transposed [k][row]
    __shared__ float wsh[2][32][36];  // [k][n]

    float acc[2][2] = {};

    const int arow = t & 31;
    const int akc  = (t >> 5) * 4;
    const int wr   = t >> 3;          // 0..31
    const int wc   = (t & 7) * 4;     // 0..28

    float4 xa = *(const float4*)&a[(m0 + arow) * DM + akc];
    float4 wa = *(const float4*)&W[wr * DM + n0 + wc];
    xs[0][akc + 0][arow] = xa.x; xs[0][akc + 1][arow] = xa.y;
    xs[0][akc + 2][arow] = xa.z; xs[0][akc + 3][arow] = xa.w;
    *(float4*)&wsh[0][wr][wc] = wa;
    __syncthreads();

    int cur = 0;
    for (int k0 = 32; k0 < DM; k0 += 32) {
        xa = *(const float4*)&a[(m0 + arow) * DM + k0 + akc];
        wa = *(const float4*)&W[(k0 + wr) * DM + n0 + wc];
        #pragma unroll
        for (int kk = 0; kk < 32; kk++) {
            float2 a2 = *(const float2*)&xs[cur][kk][ty * 2];
            float2 b2 = *(const float2*)&wsh[cur][kk][tx * 2];
            acc[0][0] += a2.x * b2.x; acc[0][1] += a2.x * b2.y;
            acc[1][0] += a2.y * b2.x; acc[1][1] += a2.y * b2.y;
        }
        const int nxt = cur ^ 1;
        xs[nxt][akc + 0][arow] = xa.x; xs[nxt][akc + 1][arow] = xa.y;
        xs[nxt][akc + 2][arow] = xa.z; xs[nxt][akc + 3][arow] = xa.w;
        *(float4*)&wsh[nxt][wr][wc] = wa;
        __syncthreads();
        cur = nxt;
    }
    #pragma unroll
    for (int kk = 0; kk < 32; kk++) {
        float2 a2 = *(const float2*)&xs[cur][kk][ty * 2];
        float2 b2 = *(const float2*)&wsh[cur][kk][tx * 2];
        acc[0][0] += a2.x * b2.x; acc[0][1] += a2.x * b2.y;
        acc[1][0] += a2.y * b2.x; acc[1][1] += a2.y * b2.y;
    }

    #pragma unroll
    for (int j = 0; j < 2; j++) {
        const int cidx = n0 + tx * 2 + j;
        const float bb = bias[cidx];
        #pragma unroll
        for (int i = 0; i < 2; i++) {
            const int row = m0 + ty * 2 + i;
            dst[row * DM + cidx] = acc[i][j] + bb;
        }
    }
}

// ---------------------------------------------------------------------------
extern "C" void kernel_launch(void* const* d_in, const int* in_sizes, int n_in,
                              void* d_out, int out_size, void* d_ws, size_t ws_size,
                              hipStream_t stream)
{
    const float* x  = (const float*)d_in[0];
    const float* Wq = (const float*)d_in[1];
    const float* bq = (const float*)d_in[2];
    const float* Wk = (const float*)d_in[3];
    const float* bk = (const float*)d_in[4];
    const float* Wv = (const float*)d_in[5];
    const float* bv = (const float*)d_in[6];
    const float* Wo = (const float*)d_in[7];
    const float* bo = (const float*)d_in[8];
    float* out = (float*)d_out;

    float* ws      = (float*)d_ws;
    float* q       = ws;                      // [8][1024][32] = 262144
    float* k       = q + 262144;
    float* v       = k + 262144;
    float* attn    = v + 262144;              // [1024][256]  = 262144
    float* part_o  = attn + 262144;           // 8*16*NS*2048 = 1048576
    float* part_l  = part_o + 1048576;        // 8*16*NS*64   = 32768
    // total ~8.5 MB

    qkv_proj_kernel<<<dim3(4, 32, 3), 256, 0, stream>>>(x, Wq, bq, Wk, bk, Wv, bv, q, k, v);
    attn_kernel<<<dim3(512), 256, 0, stream>>>(q, k, v, part_o, part_l);
    combine_kernel<<<dim3(128), 256, 0, stream>>>(part_o, part_l, attn);
    out_proj_kernel<<<dim3(8, 32), 256, 0, stream>>>(attn, Wo, bo, out);
}